// Round 8
// baseline (109.590 us; speedup 1.0000x reference)
//
#include <hip/hip_runtime.h>
#include <math.h>

#define NN 65536
#define NG 64
#define NPG 1024
#define HID 128
#define KNN 16
#define BINF 1e30f

typedef unsigned long long ull;
typedef _Float16 f16;
typedef _Float16 f16x8 __attribute__((ext_vector_type(8)));
typedef float f32x4 __attribute__((ext_vector_type(4)));

// ---------------------------------------------------------------- kNN sort + weight prep
// blocks [0,64): per-graph shuffle-bitonic sort -> sidxg + int8 rank offsets
// blocks [64,144): fragment-pack fp16 weights (prep), 1024 threads each
__global__ __launch_bounds__(1024) void k_topk(
    const float* __restrict__ x, int* __restrict__ sidxg,
    signed char* __restrict__ nbroff,
    const float* __restrict__ ig_lw, const float* __restrict__ ig_gw,
    const float* __restrict__ c1_w, const float* __restrict__ c2_w,
    f16* __restrict__ gfrag, f16* __restrict__ f1, f16* __restrict__ f2) {
    __shared__ ull key[1024];
    __shared__ float st[1024];
    __shared__ int sidx[1024];
    int g = blockIdx.x;
    if (g >= NG) {
        int gid = (g - NG) * 1024 + threadIdx.x;   // [0, 81920)
        if (gid < 16384) {
            int i = gid & 7, lane = (gid >> 3) & 63, nt = (gid >> 9) & 7;
            int kt = (gid >> 12) & 1, mat = gid >> 13;
            int k = kt * 32 + ((lane >> 4) << 3) + i;
            int c = nt * 16 + (lane & 15);
            float v = 0.0f;
            if (k < 48) v = (mat ? ig_gw : ig_lw)[k * 128 + c];
            gfrag[gid] = (f16)v;
        } else {
            int g2 = gid - 16384;
            int buf = g2 >> 15;
            int rem = g2 & 32767;
            int mat = rem >> 14;
            int r2 = rem & 16383;
            int i = r2 & 7, lane = (r2 >> 3) & 63, nt = (r2 >> 9) & 7, kt = (r2 >> 12) & 3;
            int k = kt * 32 + ((lane >> 4) << 3) + i;
            int c = nt * 16 + (lane & 15);
            const float* cw = buf ? c2_w : c1_w;
            float top = cw[k * 128 + c];
            float bot = cw[(128 + k) * 128 + c];
            float v = mat ? bot : (top - bot);
            (buf ? f2 : f1)[rem] = (f16)v;
        }
        return;
    }
    int i = threadIdx.x;
    float t = x[(size_t)(g * NPG + i) * 17];
    unsigned ub = __float_as_uint(t);
    ub = (ub & 0x80000000u) ? ~ub : (ub | 0x80000000u);   // order-preserving map
    ull kk = ((ull)ub << 32) | (unsigned)i;

    for (int k = 2; k <= 1024; k <<= 1) {
        for (int j = k >> 1; j > 0; j >>= 1) {
            ull pv;
            if (j >= 64) {
                key[i] = kk;
                __syncthreads();
                pv = key[i ^ j];
                __syncthreads();
            } else {
                pv = __shfl_xor(kk, j, 64);
            }
            bool up = ((i & k) == 0);
            bool low = ((i & j) == 0);
            ull mn = kk < pv ? kk : pv;
            ull mx = kk < pv ? pv : kk;
            kk = (up == low) ? mn : mx;
        }
    }
    int oi = (int)(kk & 0xffffffffu);
    st[i] = x[(size_t)(g * NPG + oi) * 17];
    sidx[i] = oi;
    sidxg[g * NPG + i] = g * NPG + oi;
    __syncthreads();

    // two-pointer merge in rank space; offsets in [-16,16]
    float tt = st[i];
    int L = i - 1, R = i + 1;
    signed char* out = nbroff + (size_t)(g * NPG + i) * KNN;
#pragma unroll
    for (int q = 0; q < KNN; q++) {
        float dl = (L >= 0)   ? (tt - st[L]) : BINF;
        float dr = (R < NPG) ? (st[R] - tt) : BINF;
        bool left;
        if (dl < dr) left = true;
        else if (dr < dl) left = false;
        else left = (sidx[L] < sidx[R]);   // tie: lower original index (lax.top_k)
        int jr;
        if (left) { jr = L; L--; }
        else      { jr = R; R++; }
        out[q] = (signed char)(jr - i);
    }
}

// ---------------------------------------------------------------- fused GLU + conv1
// H tile lives only in LDS; A1 = H@W1+b, B1 = H@W2 written f16 (rank order).
__global__ __launch_bounds__(256) void k_fuse1(
    const float* __restrict__ x, const float* __restrict__ te_w,
    const float* __restrict__ te_b, const f16x8* __restrict__ gfrag,
    const float* __restrict__ bl, const float* __restrict__ bg,
    const int* __restrict__ sidxg, const f16x8* __restrict__ wfrag,
    const float* __restrict__ cb, f16* __restrict__ A, f16* __restrict__ B) {
    __shared__ f16x8 XL[4 * 2 * 64];          // Z fragments [mf][kt][lane]
    __shared__ f16 ht[64 * 128];              // XOR-swizzled H tile
    int tid = threadIdx.x;
    int r0 = blockIdx.x * 64;
#pragma unroll
    for (int p = 0; p < 2; p++) {
        int idx = tid + p * 256;              // [0,512)
        int row = idx >> 3, kq = idx & 7;
        int node = sidxg[r0 + row];
        f16x8 h;
        if (kq < 2) {
            const float* xr = x + (size_t)node * 17 + 1 + kq * 8;
#pragma unroll
            for (int i = 0; i < 8; i++) h[i] = (f16)xr[i];
        } else if (kq < 6) {
            float t = x[(size_t)node * 17];
            int j0 = (kq - 2) * 8;
#pragma unroll
            for (int i = 0; i < 8; i++) h[i] = (f16)fmaf(t, te_w[j0 + i], te_b[j0 + i]);
        } else {
#pragma unroll
            for (int i = 0; i < 8; i++) h[i] = (f16)0.0f;
        }
        int mf = row >> 4, kt = kq >> 2, lane = ((kq & 3) << 4) | (row & 15);
        XL[(mf * 2 + kt) * 64 + lane] = h;
    }
    __syncthreads();
    int w = tid >> 6, lane = tid & 63;
    f32x4 acc[2][2][4];
#pragma unroll
    for (int o = 0; o < 2; o++)
#pragma unroll
        for (int j = 0; j < 2; j++)
#pragma unroll
            for (int mf = 0; mf < 4; mf++) acc[o][j][mf] = (f32x4){0.f, 0.f, 0.f, 0.f};
#pragma unroll 1
    for (int kt = 0; kt < 2; kt++) {
        f16x8 wf0[2], wf1[2], xa[4];
#pragma unroll
        for (int j = 0; j < 2; j++) {
            wf0[j] = gfrag[((0 * 2 + kt) * 8 + (w * 2 + j)) * 64 + lane];
            wf1[j] = gfrag[((1 * 2 + kt) * 8 + (w * 2 + j)) * 64 + lane];
        }
#pragma unroll
        for (int mf = 0; mf < 4; mf++) xa[mf] = XL[(mf * 2 + kt) * 64 + lane];
#pragma unroll
        for (int mf = 0; mf < 4; mf++)
#pragma unroll
            for (int j = 0; j < 2; j++) {
                acc[0][j][mf] = __builtin_amdgcn_mfma_f32_16x16x32_f16(xa[mf], wf0[j], acc[0][j][mf], 0, 0, 0);
                acc[1][j][mf] = __builtin_amdgcn_mfma_f32_16x16x32_f16(xa[mf], wf1[j], acc[1][j][mf], 0, 0, 0);
            }
    }
    // GLU epilogue -> swizzled LDS tile
#pragma unroll
    for (int j = 0; j < 2; j++) {
        int col = w * 32 + j * 16 + (lane & 15);
        float bbl = bl[col], bbg = bg[col];
#pragma unroll
        for (int mf = 0; mf < 4; mf++) {
            int rloc = mf * 16 + ((lane >> 4) << 2);
#pragma unroll
            for (int q = 0; q < 4; q++) {
                float lin = acc[0][j][mf][q] + bbl;
                float gat = acc[1][j][mf][q] + bbg;
                int row = rloc + q;
                ht[(row * 128 + col) ^ ((row & 7) << 3)] = (f16)(lin / (1.0f + expf(-gat)));
            }
        }
    }
    __syncthreads();
    // conv1 dual GEMM from ht
#pragma unroll
    for (int o = 0; o < 2; o++)
#pragma unroll
        for (int j = 0; j < 2; j++)
#pragma unroll
            for (int mf = 0; mf < 4; mf++) acc[o][j][mf] = (f32x4){0.f, 0.f, 0.f, 0.f};
    int row16 = lane & 15, kslot = lane >> 4;
    int swz = (row16 & 7) << 3;
#pragma unroll 1
    for (int kt = 0; kt < 4; kt++) {
        f16x8 wf0[2], wf1[2], xa[4];
#pragma unroll
        for (int j = 0; j < 2; j++) {
            wf0[j] = wfrag[((0 * 4 + kt) * 8 + (w * 2 + j)) * 64 + lane];
            wf1[j] = wfrag[((1 * 4 + kt) * 8 + (w * 2 + j)) * 64 + lane];
        }
#pragma unroll
        for (int mf = 0; mf < 4; mf++)
            xa[mf] = *(const f16x8*)&ht[((mf * 16 + row16) * 128 + kt * 32 + kslot * 8) ^ swz];
#pragma unroll
        for (int mf = 0; mf < 4; mf++)
#pragma unroll
            for (int j = 0; j < 2; j++) {
                acc[0][j][mf] = __builtin_amdgcn_mfma_f32_16x16x32_f16(xa[mf], wf0[j], acc[0][j][mf], 0, 0, 0);
                acc[1][j][mf] = __builtin_amdgcn_mfma_f32_16x16x32_f16(xa[mf], wf1[j], acc[1][j][mf], 0, 0, 0);
            }
    }
#pragma unroll
    for (int j = 0; j < 2; j++) {
        int col = w * 32 + j * 16 + (lane & 15);
        float bias = cb[col];
#pragma unroll
        for (int mf = 0; mf < 4; mf++) {
            int rbase = r0 + mf * 16 + ((lane >> 4) << 2);
#pragma unroll
            for (int q = 0; q < 4; q++) {
                A[(size_t)(rbase + q) * 128 + col] = (f16)(acc[0][j][mf][q] + bias);
                B[(size_t)(rbase + q) * 128 + col] = (f16)acc[1][j][mf][q];
            }
        }
    }
}

// ---------------------------------------------------------------- conv2 fused
// x1 = relu(A1 + window-max B1) (LDS only); pool x1 partials; A2/B2 = x1@W'.
// Bwin byte-swizzled ^((row&7)<<5): rows 8 banks apart -> no 4-way conflicts.
__global__ __launch_bounds__(256) void k_conv2f(
    const f16* __restrict__ A1, const f16* __restrict__ B1,
    const signed char* __restrict__ nbroff, const f16x8* __restrict__ wfrag,
    const float* __restrict__ cb, f16* __restrict__ A2, f16* __restrict__ B2,
    float* __restrict__ partM1, float* __restrict__ partS1) {
    __shared__ f16 Bwin[96 * 128];            // rank window [r0-16, r0+80), swizzled
    __shared__ f16 x1t[64 * 128];             // XOR-swizzled GEMM input tile
    __shared__ float redM[4 * 128];
    __shared__ float redS[4 * 128];
    char* bw = (char*)Bwin;
    int tid = threadIdx.x;
    int bx = blockIdx.x;
    int r0 = bx * 64;
    int r0loc = (bx & 15) * 64;
#pragma unroll
    for (int p = 0; p < 6; p++) {
        int idx = tid + p * 256;              // [0,1536)
        int row = idx >> 4, kq = idx & 15;
        int gl = r0loc - 16 + row;
        f16x8 v;
#pragma unroll
        for (int i = 0; i < 8; i++) v[i] = (f16)0.0f;
        if (gl >= 0 && gl < NPG)
            v = *(const f16x8*)(B1 + (size_t)(r0 - 16 + row) * 128 + kq * 8);
        *(f16x8*)(bw + ((row * 256 + kq * 16) ^ ((row & 7) << 5))) = v;
    }
    __syncthreads();
    int w = tid >> 6, lane = tid & 63;
    int rquad = lane >> 4;                    // row within 4-row group
    int c0 = (lane & 15) * 8;                 // channel octet
    float pm[8], ps[8];
#pragma unroll
    for (int i = 0; i < 8; i++) { pm[i] = -BINF; ps[i] = 0.f; }
#pragma unroll 1
    for (int rr = 0; rr < 4; rr++) {
        int row = w * 16 + rr * 4 + rquad;
        int grow = r0 + row;
        int4 ov = *(const int4*)(nbroff + (size_t)grow * 16);
        const int* ow = (const int*)&ov;
        f16x8 m;
#pragma unroll
        for (int i = 0; i < 8; i++) m[i] = (f16)(-INFINITY);
#pragma unroll
        for (int q = 0; q < 16; q++) {
            int off = (int)(signed char)((ow[q >> 2] >> ((q & 3) * 8)) & 0xff);
            int ar = row + 16 + off;
            f16x8 bv = *(const f16x8*)(bw + ((ar * 256 + c0 * 2) ^ ((ar & 7) << 5)));
            m = __builtin_elementwise_max(m, bv);
        }
        f16x8 av = *(const f16x8*)(A1 + (size_t)grow * 128 + c0);
        f16x8 ou;
#pragma unroll
        for (int i = 0; i < 8; i++) {
            float v = fmaxf((float)av[i] + (float)m[i], 0.0f);
            pm[i] = fmaxf(pm[i], v);
            ps[i] += v;
            ou[i] = (f16)v;
        }
        int idx = (row * 128 + c0) ^ ((row & 7) << 3);
        *(f16x8*)&x1t[idx] = ou;
    }
    // pool reduce: across rquad groups via shuffles, then across waves via LDS
#pragma unroll
    for (int i = 0; i < 8; i++) {
        pm[i] = fmaxf(pm[i], __shfl_xor(pm[i], 16));
        pm[i] = fmaxf(pm[i], __shfl_xor(pm[i], 32));
        ps[i] += __shfl_xor(ps[i], 16);
        ps[i] += __shfl_xor(ps[i], 32);
    }
    if (rquad == 0) {
#pragma unroll
        for (int i = 0; i < 8; i++) {
            redM[w * 128 + c0 + i] = pm[i];
            redS[w * 128 + c0 + i] = ps[i];
        }
    }
    __syncthreads();
    if (tid < 128) {
        float M = -BINF, S = 0.f;
#pragma unroll
        for (int w2 = 0; w2 < 4; w2++) {
            M = fmaxf(M, redM[w2 * 128 + tid]);
            S += redS[w2 * 128 + tid];
        }
        partM1[(size_t)bx * 128 + tid] = M;
        partS1[(size_t)bx * 128 + tid] = S;
    }
    f32x4 acc[2][2][4];
#pragma unroll
    for (int o = 0; o < 2; o++)
#pragma unroll
        for (int j = 0; j < 2; j++)
#pragma unroll
            for (int mf = 0; mf < 4; mf++) acc[o][j][mf] = (f32x4){0.f, 0.f, 0.f, 0.f};
    int row16 = lane & 15, kslot = lane >> 4;
    int swz = (row16 & 7) << 3;
#pragma unroll 1
    for (int kt = 0; kt < 4; kt++) {
        f16x8 wf0[2], wf1[2], xa[4];
#pragma unroll
        for (int j = 0; j < 2; j++) {
            wf0[j] = wfrag[((0 * 4 + kt) * 8 + (w * 2 + j)) * 64 + lane];
            wf1[j] = wfrag[((1 * 4 + kt) * 8 + (w * 2 + j)) * 64 + lane];
        }
#pragma unroll
        for (int mf = 0; mf < 4; mf++)
            xa[mf] = *(const f16x8*)&x1t[((mf * 16 + row16) * 128 + kt * 32 + kslot * 8) ^ swz];
#pragma unroll
        for (int mf = 0; mf < 4; mf++)
#pragma unroll
            for (int j = 0; j < 2; j++) {
                acc[0][j][mf] = __builtin_amdgcn_mfma_f32_16x16x32_f16(xa[mf], wf0[j], acc[0][j][mf], 0, 0, 0);
                acc[1][j][mf] = __builtin_amdgcn_mfma_f32_16x16x32_f16(xa[mf], wf1[j], acc[1][j][mf], 0, 0, 0);
            }
    }
#pragma unroll
    for (int j = 0; j < 2; j++) {
        int col = w * 32 + j * 16 + (lane & 15);
        float bias = cb[col];
#pragma unroll
        for (int mf = 0; mf < 4; mf++) {
            int rbase = r0 + mf * 16 + ((lane >> 4) << 2);
#pragma unroll
            for (int q = 0; q < 4; q++) {
                A2[(size_t)(rbase + q) * 128 + col] = (f16)(acc[0][j][mf][q] + bias);
                B2[(size_t)(rbase + q) * 128 + col] = (f16)acc[1][j][mf][q];
            }
        }
    }
}

// ---------------------------------------------------------------- gather2 + pool
// x2 computed in f32 registers from A2 + window-max B2; pooled, never stored.
__global__ __launch_bounds__(256) void k_gather2p(
    const f16* __restrict__ A2, const f16* __restrict__ B2,
    const signed char* __restrict__ nbroff,
    float* __restrict__ partM2, float* __restrict__ partS2) {
    __shared__ f16 Bwin[96 * 128];            // swizzled
    __shared__ float redM[4 * 128];
    __shared__ float redS[4 * 128];
    char* bw = (char*)Bwin;
    int tid = threadIdx.x;
    int bx = blockIdx.x;
    int r0 = bx * 64;
    int r0loc = (bx & 15) * 64;
#pragma unroll
    for (int p = 0; p < 6; p++) {
        int idx = tid + p * 256;
        int row = idx >> 4, kq = idx & 15;
        int gl = r0loc - 16 + row;
        f16x8 v;
#pragma unroll
        for (int i = 0; i < 8; i++) v[i] = (f16)0.0f;
        if (gl >= 0 && gl < NPG)
            v = *(const f16x8*)(B2 + (size_t)(r0 - 16 + row) * 128 + kq * 8);
        *(f16x8*)(bw + ((row * 256 + kq * 16) ^ ((row & 7) << 5))) = v;
    }
    __syncthreads();
    int w = tid >> 6, lane = tid & 63;
    int rquad = lane >> 4;
    int c0 = (lane & 15) * 8;
    float pm[8], ps[8];
#pragma unroll
    for (int i = 0; i < 8; i++) { pm[i] = -BINF; ps[i] = 0.f; }
#pragma unroll 1
    for (int rr = 0; rr < 4; rr++) {
        int row = w * 16 + rr * 4 + rquad;
        int grow = r0 + row;
        int4 ov = *(const int4*)(nbroff + (size_t)grow * 16);
        const int* ow = (const int*)&ov;
        f16x8 m;
#pragma unroll
        for (int i = 0; i < 8; i++) m[i] = (f16)(-INFINITY);
#pragma unroll
        for (int q = 0; q < 16; q++) {
            int off = (int)(signed char)((ow[q >> 2] >> ((q & 3) * 8)) & 0xff);
            int ar = row + 16 + off;
            f16x8 bv = *(const f16x8*)(bw + ((ar * 256 + c0 * 2) ^ ((ar & 7) << 5)));
            m = __builtin_elementwise_max(m, bv);
        }
        f16x8 av = *(const f16x8*)(A2 + (size_t)grow * 128 + c0);
#pragma unroll
        for (int i = 0; i < 8; i++) {
            float v = fmaxf((float)av[i] + (float)m[i], 0.0f);
            pm[i] = fmaxf(pm[i], v);
            ps[i] += v;
        }
    }
#pragma unroll
    for (int i = 0; i < 8; i++) {
        pm[i] = fmaxf(pm[i], __shfl_xor(pm[i], 16));
        pm[i] = fmaxf(pm[i], __shfl_xor(pm[i], 32));
        ps[i] += __shfl_xor(ps[i], 16);
        ps[i] += __shfl_xor(ps[i], 32);
    }
    if (rquad == 0) {
#pragma unroll
        for (int i = 0; i < 8; i++) {
            redM[w * 128 + c0 + i] = pm[i];
            redS[w * 128 + c0 + i] = ps[i];
        }
    }
    __syncthreads();
    if (tid < 128) {
        float M = -BINF, S = 0.f;
#pragma unroll
        for (int w2 = 0; w2 < 4; w2++) {
            M = fmaxf(M, redM[w2 * 128 + tid]);
            S += redS[w2 * 128 + tid];
        }
        partM2[(size_t)bx * 128 + tid] = M;
        partS2[(size_t)bx * 128 + tid] = S;
    }
}

// ---------------------------------------------------------------- final head
__global__ __launch_bounds__(256) void k_final(const float* __restrict__ partM1,
                                               const float* __restrict__ partS1,
                                               const float* __restrict__ partM2,
                                               const float* __restrict__ partS2,
                                               const float* __restrict__ fg_lw,
                                               const float* __restrict__ fg_lb,
                                               const float* __restrict__ fg_gw,
                                               const float* __restrict__ fg_gb,
                                               const float* __restrict__ out_w,
                                               const float* __restrict__ out_b,
                                               float* __restrict__ out) {
    __shared__ float pooled[512];
    __shared__ float linv[128], gatev[128];
    __shared__ float gluv[128];
    __shared__ float lg[2];
    int g = blockIdx.x, tid = threadIdx.x;

    const float* pM = (tid < 128) ? partM1 : partM2;
    const float* pS = (tid < 128) ? partS1 : partS2;
    int cc = tid & 127;
    float mx = -BINF, sm = 0.0f;
    for (int ch = 0; ch < 16; ch++) {
        mx = fmaxf(mx, pM[(size_t)(g * 16 + ch) * 128 + cc]);
        sm += pS[(size_t)(g * 16 + ch) * 128 + cc];
    }
    pooled[tid] = mx;
    pooled[256 + tid] = sm * (1.0f / 1024.0f);
    __syncthreads();

    float acc = 0.0f;
    if (tid < 128) {
        for (int k = 0; k < 512; k++) acc = fmaf(pooled[k], fg_lw[k * 128 + tid], acc);
        linv[tid] = acc + fg_lb[tid];
    } else {
        int c = tid - 128;
        for (int k = 0; k < 512; k++) acc = fmaf(pooled[k], fg_gw[k * 128 + c], acc);
        gatev[c] = acc + fg_gb[c];
    }
    __syncthreads();
    if (tid < 128) gluv[tid] = linv[tid] / (1.0f + expf(-gatev[tid]));
    __syncthreads();
    if (tid < 2) {
        float s = out_b[tid];
        for (int c = 0; c < 128; c++) s = fmaf(gluv[c], out_w[c * 2 + tid], s);
        lg[tid] = s;
    }
    __syncthreads();
    if (tid < 2) {
        float m = fmaxf(lg[0], lg[1]);
        float lse = m + logf(expf(lg[0] - m) + expf(lg[1] - m));
        out[g * 2 + tid] = lg[tid] - lse;
    }
}

// ---------------------------------------------------------------- launch
extern "C" void kernel_launch(void* const* d_in, const int* in_sizes, int n_in,
                              void* d_out, int out_size, void* d_ws, size_t ws_size,
                              hipStream_t stream) {
    const float* x     = (const float*)d_in[0];
    const float* te_w  = (const float*)d_in[1];
    const float* te_b  = (const float*)d_in[2];
    const float* ig_lw = (const float*)d_in[3];
    const float* ig_lb = (const float*)d_in[4];
    const float* ig_gw = (const float*)d_in[5];
    const float* ig_gb = (const float*)d_in[6];
    const float* c1_w  = (const float*)d_in[7];
    const float* c1_b  = (const float*)d_in[8];
    const float* c2_w  = (const float*)d_in[9];
    const float* c2_b  = (const float*)d_in[10];
    const float* fg_lw = (const float*)d_in[11];
    const float* fg_lb = (const float*)d_in[12];
    const float* fg_gw = (const float*)d_in[13];
    const float* fg_gb = (const float*)d_in[14];
    const float* out_w = (const float*)d_in[15];
    const float* out_b = (const float*)d_in[16];
    float* out = (float*)d_out;

    // workspace layout (~67 MB)
    char* p = (char*)d_ws;
    const size_t T16 = (size_t)NN * HID * sizeof(f16);   // 16 MB
    f16* A1 = (f16*)p; p += T16;
    f16* B1 = (f16*)p; p += T16;
    f16* A2 = (f16*)p; p += T16;
    f16* B2 = (f16*)p; p += T16;
    int* sidxg = (int*)p;            p += (size_t)NN * 4;
    signed char* nbroff = (signed char*)p; p += (size_t)NN * KNN;
    float* partM1 = (float*)p;       p += (size_t)1024 * 128 * 4;
    float* partS1 = (float*)p;       p += (size_t)1024 * 128 * 4;
    float* partM2 = (float*)p;       p += (size_t)1024 * 128 * 4;
    float* partS2 = (float*)p;       p += (size_t)1024 * 128 * 4;
    f16* gfrag = (f16*)p;            p += 16384 * 2;
    f16* f1 = (f16*)p;               p += 32768 * 2;
    f16* f2 = (f16*)p;               p += 32768 * 2;

    k_topk<<<NG + 80, 1024, 0, stream>>>(x, sidxg, nbroff, ig_lw, ig_gw,
                                         c1_w, c2_w, gfrag, f1, f2);
    k_fuse1<<<NN / 64, 256, 0, stream>>>(x, te_w, te_b, (const f16x8*)gfrag,
                                         ig_lb, ig_gb, sidxg, (const f16x8*)f1,
                                         c1_b, A1, B1);
    k_conv2f<<<NN / 64, 256, 0, stream>>>(A1, B1, nbroff, (const f16x8*)f2,
                                          c2_b, A2, B2, partM1, partS1);
    k_gather2p<<<NN / 64, 256, 0, stream>>>(A2, B2, nbroff, partM2, partS2);
    k_final<<<NG, 256, 0, stream>>>(partM1, partS1, partM2, partS2,
                                    fg_lw, fg_lb, fg_gw, fg_gb, out_w, out_b, out);
}

// Round 9
// 107.066 us; speedup vs baseline: 1.0236x; 1.0236x over previous
//
#include <hip/hip_runtime.h>
#include <math.h>

#define NN 65536
#define NG 64
#define NPG 1024
#define HID 128
#define KNN 16
#define BINF 1e30f
#define BWS 272            // padded LDS row stride (bytes): 17*16B -> dRow=4 => dBank=16

typedef unsigned long long ull;
typedef _Float16 f16;
typedef _Float16 f16x8 __attribute__((ext_vector_type(8)));
typedef float f32x4 __attribute__((ext_vector_type(4)));

// ---------------------------------------------------------------- kNN sort + weight prep
__global__ __launch_bounds__(1024) void k_topk(
    const float* __restrict__ x, int* __restrict__ sidxg,
    signed char* __restrict__ nbroff,
    const float* __restrict__ ig_lw, const float* __restrict__ ig_gw,
    const float* __restrict__ c1_w, const float* __restrict__ c2_w,
    f16* __restrict__ gfrag, f16* __restrict__ f1, f16* __restrict__ f2) {
    __shared__ ull key[1024];
    __shared__ float st[1024];
    __shared__ int sidx[1024];
    int g = blockIdx.x;
    if (g >= NG) {
        int gid = (g - NG) * 1024 + threadIdx.x;   // [0, 81920)
        if (gid < 16384) {
            int i = gid & 7, lane = (gid >> 3) & 63, nt = (gid >> 9) & 7;
            int kt = (gid >> 12) & 1, mat = gid >> 13;
            int k = kt * 32 + ((lane >> 4) << 3) + i;
            int c = nt * 16 + (lane & 15);
            float v = 0.0f;
            if (k < 48) v = (mat ? ig_gw : ig_lw)[k * 128 + c];
            gfrag[gid] = (f16)v;
        } else {
            int g2 = gid - 16384;
            int buf = g2 >> 15;
            int rem = g2 & 32767;
            int mat = rem >> 14;
            int r2 = rem & 16383;
            int i = r2 & 7, lane = (r2 >> 3) & 63, nt = (r2 >> 9) & 7, kt = (r2 >> 12) & 3;
            int k = kt * 32 + ((lane >> 4) << 3) + i;
            int c = nt * 16 + (lane & 15);
            const float* cw = buf ? c2_w : c1_w;
            float top = cw[k * 128 + c];
            float bot = cw[(128 + k) * 128 + c];
            float v = mat ? bot : (top - bot);
            (buf ? f2 : f1)[rem] = (f16)v;
        }
        return;
    }
    int i = threadIdx.x;
    float t = x[(size_t)(g * NPG + i) * 17];
    unsigned ub = __float_as_uint(t);
    ub = (ub & 0x80000000u) ? ~ub : (ub | 0x80000000u);   // order-preserving map
    ull kk = ((ull)ub << 32) | (unsigned)i;

    for (int k = 2; k <= 1024; k <<= 1) {
        for (int j = k >> 1; j > 0; j >>= 1) {
            ull pv;
            if (j >= 64) {
                key[i] = kk;
                __syncthreads();
                pv = key[i ^ j];
                __syncthreads();
            } else {
                pv = __shfl_xor(kk, j, 64);
            }
            bool up = ((i & k) == 0);
            bool low = ((i & j) == 0);
            ull mn = kk < pv ? kk : pv;
            ull mx = kk < pv ? pv : kk;
            kk = (up == low) ? mn : mx;
        }
    }
    int oi = (int)(kk & 0xffffffffu);
    st[i] = x[(size_t)(g * NPG + oi) * 17];
    sidx[i] = oi;
    sidxg[g * NPG + i] = g * NPG + oi;
    __syncthreads();

    // two-pointer merge in rank space; offsets in [-16,16]
    float tt = st[i];
    int L = i - 1, R = i + 1;
    signed char* out = nbroff + (size_t)(g * NPG + i) * KNN;
#pragma unroll
    for (int q = 0; q < KNN; q++) {
        float dl = (L >= 0)   ? (tt - st[L]) : BINF;
        float dr = (R < NPG) ? (st[R] - tt) : BINF;
        bool left;
        if (dl < dr) left = true;
        else if (dr < dl) left = false;
        else left = (sidx[L] < sidx[R]);   // tie: lower original index (lax.top_k)
        int jr;
        if (left) { jr = L; L--; }
        else      { jr = R; R++; }
        out[q] = (signed char)(jr - i);
    }
}

// ---------------------------------------------------------------- fused GLU + conv1
__global__ __launch_bounds__(256) void k_fuse1(
    const float* __restrict__ x, const float* __restrict__ te_w,
    const float* __restrict__ te_b, const f16x8* __restrict__ gfrag,
    const float* __restrict__ bl, const float* __restrict__ bg,
    const int* __restrict__ sidxg, const f16x8* __restrict__ wfrag,
    const float* __restrict__ cb, f16* __restrict__ A, f16* __restrict__ B) {
    __shared__ f16x8 XL[4 * 2 * 64];          // Z fragments [mf][kt][lane]
    __shared__ f16 ht[64 * 128];              // XOR-swizzled H tile
    int tid = threadIdx.x;
    int r0 = blockIdx.x * 64;
#pragma unroll
    for (int p = 0; p < 2; p++) {
        int idx = tid + p * 256;              // [0,512)
        int row = idx >> 3, kq = idx & 7;
        int node = sidxg[r0 + row];
        f16x8 h;
        if (kq < 2) {
            const float* xr = x + (size_t)node * 17 + 1 + kq * 8;
#pragma unroll
            for (int i = 0; i < 8; i++) h[i] = (f16)xr[i];
        } else if (kq < 6) {
            float t = x[(size_t)node * 17];
            int j0 = (kq - 2) * 8;
#pragma unroll
            for (int i = 0; i < 8; i++) h[i] = (f16)fmaf(t, te_w[j0 + i], te_b[j0 + i]);
        } else {
#pragma unroll
            for (int i = 0; i < 8; i++) h[i] = (f16)0.0f;
        }
        int mf = row >> 4, kt = kq >> 2, lane = ((kq & 3) << 4) | (row & 15);
        XL[(mf * 2 + kt) * 64 + lane] = h;
    }
    __syncthreads();
    int w = tid >> 6, lane = tid & 63;
    f32x4 acc[2][2][4];
#pragma unroll
    for (int o = 0; o < 2; o++)
#pragma unroll
        for (int j = 0; j < 2; j++)
#pragma unroll
            for (int mf = 0; mf < 4; mf++) acc[o][j][mf] = (f32x4){0.f, 0.f, 0.f, 0.f};
#pragma unroll 1
    for (int kt = 0; kt < 2; kt++) {
        f16x8 wf0[2], wf1[2], xa[4];
#pragma unroll
        for (int j = 0; j < 2; j++) {
            wf0[j] = gfrag[((0 * 2 + kt) * 8 + (w * 2 + j)) * 64 + lane];
            wf1[j] = gfrag[((1 * 2 + kt) * 8 + (w * 2 + j)) * 64 + lane];
        }
#pragma unroll
        for (int mf = 0; mf < 4; mf++) xa[mf] = XL[(mf * 2 + kt) * 64 + lane];
#pragma unroll
        for (int mf = 0; mf < 4; mf++)
#pragma unroll
            for (int j = 0; j < 2; j++) {
                acc[0][j][mf] = __builtin_amdgcn_mfma_f32_16x16x32_f16(xa[mf], wf0[j], acc[0][j][mf], 0, 0, 0);
                acc[1][j][mf] = __builtin_amdgcn_mfma_f32_16x16x32_f16(xa[mf], wf1[j], acc[1][j][mf], 0, 0, 0);
            }
    }
    // GLU epilogue -> swizzled LDS tile
#pragma unroll
    for (int j = 0; j < 2; j++) {
        int col = w * 32 + j * 16 + (lane & 15);
        float bbl = bl[col], bbg = bg[col];
#pragma unroll
        for (int mf = 0; mf < 4; mf++) {
            int rloc = mf * 16 + ((lane >> 4) << 2);
#pragma unroll
            for (int q = 0; q < 4; q++) {
                float lin = acc[0][j][mf][q] + bbl;
                float gat = acc[1][j][mf][q] + bbg;
                int row = rloc + q;
                ht[(row * 128 + col) ^ ((row & 7) << 3)] = (f16)(lin / (1.0f + expf(-gat)));
            }
        }
    }
    __syncthreads();
    // conv1 dual GEMM from ht
#pragma unroll
    for (int o = 0; o < 2; o++)
#pragma unroll
        for (int j = 0; j < 2; j++)
#pragma unroll
            for (int mf = 0; mf < 4; mf++) acc[o][j][mf] = (f32x4){0.f, 0.f, 0.f, 0.f};
    int row16 = lane & 15, kslot = lane >> 4;
    int swz = (row16 & 7) << 3;
#pragma unroll 1
    for (int kt = 0; kt < 4; kt++) {
        f16x8 wf0[2], wf1[2], xa[4];
#pragma unroll
        for (int j = 0; j < 2; j++) {
            wf0[j] = wfrag[((0 * 4 + kt) * 8 + (w * 2 + j)) * 64 + lane];
            wf1[j] = wfrag[((1 * 4 + kt) * 8 + (w * 2 + j)) * 64 + lane];
        }
#pragma unroll
        for (int mf = 0; mf < 4; mf++)
            xa[mf] = *(const f16x8*)&ht[((mf * 16 + row16) * 128 + kt * 32 + kslot * 8) ^ swz];
#pragma unroll
        for (int mf = 0; mf < 4; mf++)
#pragma unroll
            for (int j = 0; j < 2; j++) {
                acc[0][j][mf] = __builtin_amdgcn_mfma_f32_16x16x32_f16(xa[mf], wf0[j], acc[0][j][mf], 0, 0, 0);
                acc[1][j][mf] = __builtin_amdgcn_mfma_f32_16x16x32_f16(xa[mf], wf1[j], acc[1][j][mf], 0, 0, 0);
            }
    }
#pragma unroll
    for (int j = 0; j < 2; j++) {
        int col = w * 32 + j * 16 + (lane & 15);
        float bias = cb[col];
#pragma unroll
        for (int mf = 0; mf < 4; mf++) {
            int rbase = r0 + mf * 16 + ((lane >> 4) << 2);
#pragma unroll
            for (int q = 0; q < 4; q++) {
                A[(size_t)(rbase + q) * 128 + col] = (f16)(acc[0][j][mf][q] + bias);
                B[(size_t)(rbase + q) * 128 + col] = (f16)acc[1][j][mf][q];
            }
        }
    }
}

// ---------------------------------------------------------------- conv2 + gather2 + pools (halo recompute)
// Per block: halo rows [r0-16, r0+80). x1 = relu(A1 + win-max B1) in LDS;
// pool x1 interior; A2/B2 = x1 @ W' kept in LDS; x2 = relu(A2 + win-max B2)
// pooled in-register. A2/B2 never touch HBM.
__global__ __launch_bounds__(256) void k_megac2(
    const f16* __restrict__ A1, const f16* __restrict__ B1,
    const signed char* __restrict__ nbroff, const f16x8* __restrict__ wfrag,
    const float* __restrict__ cb,
    float* __restrict__ partM1, float* __restrict__ partS1,
    float* __restrict__ partM2, float* __restrict__ partS2) {
    __shared__ char SM[80896];
    char* bw  = SM;                            // B1 window: 128 rows x BWS (ranks r0-32+h)
    char* b2  = SM;                            // B2: 96 rows x BWS (aliases bw, after gather1)
    f16*  x1t = (f16*)(SM + 34816);            // 96x128 f16, XOR-swizzled (24576 B)
    char* a2  = SM + 59392;                    // A2: 64 rows x BWS (17408 B)
    float* redM = (float*)(SM + 76800);        // 4*128
    float* redS = (float*)(SM + 78848);        // 4*128

    int tid = threadIdx.x;
    int bx = blockIdx.x;
    int r0 = bx * 64;
    int r0loc = (bx & 15) * 64;
    int gbase = r0 - r0loc;                    // graph base row

    // ---- stage B1 window ranks [r0loc-32, r0loc+96)
#pragma unroll
    for (int p = 0; p < 8; p++) {
        int idx = tid + p * 256;               // [0,2048)
        int row = idx >> 4, kq = idx & 15;
        int gl = r0loc - 32 + row;
        f16x8 v;
#pragma unroll
        for (int i = 0; i < 8; i++) v[i] = (f16)0.0f;
        if (gl >= 0 && gl < NPG)
            v = *(const f16x8*)(B1 + (size_t)(gbase + gl) * 128 + kq * 8);
        *(f16x8*)(bw + row * BWS + kq * 16) = v;
    }
    __syncthreads();

    int w = tid >> 6, lane = tid & 63;
    int rquad = lane >> 4;
    int c0 = (lane & 15) * 8;

    // ---- gather1: x1 for 96 halo rows; pool interior [16,80)
    float pm[8], ps[8];
#pragma unroll
    for (int i = 0; i < 8; i++) { pm[i] = -BINF; ps[i] = 0.f; }
#pragma unroll 1
    for (int rr = 0; rr < 6; rr++) {
        int row = w * 24 + rr * 4 + rquad;     // [0,96)
        int gl = r0loc - 16 + row;
        f16x8 ou;
#pragma unroll
        for (int i = 0; i < 8; i++) ou[i] = (f16)0.0f;
        if (gl >= 0 && gl < NPG) {
            int grow = gbase + gl;
            int4 ov = *(const int4*)(nbroff + (size_t)grow * 16);
            const int* ow = (const int*)&ov;
            f16x8 m;
#pragma unroll
            for (int i = 0; i < 8; i++) m[i] = (f16)(-INFINITY);
#pragma unroll
            for (int q = 0; q < 16; q++) {
                int off = (int)(signed char)((ow[q >> 2] >> ((q & 3) * 8)) & 0xff);
                int hn = row + 16 + off;       // [0,128)
                f16x8 bv = *(const f16x8*)(bw + hn * BWS + c0 * 2);
                m = __builtin_elementwise_max(m, bv);
            }
            f16x8 av = *(const f16x8*)(A1 + (size_t)grow * 128 + c0);
            bool interior = (row >= 16) && (row < 80);
#pragma unroll
            for (int i = 0; i < 8; i++) {
                float v = fmaxf((float)av[i] + (float)m[i], 0.0f);
                ou[i] = (f16)v;
                if (interior) { pm[i] = fmaxf(pm[i], v); ps[i] += v; }
            }
        }
        int idx = (row * 128 + c0) ^ ((row & 7) << 3);
        *(f16x8*)&x1t[idx] = ou;
    }
    // x1 pool reduce
#pragma unroll
    for (int i = 0; i < 8; i++) {
        pm[i] = fmaxf(pm[i], __shfl_xor(pm[i], 16));
        pm[i] = fmaxf(pm[i], __shfl_xor(pm[i], 32));
        ps[i] += __shfl_xor(ps[i], 16);
        ps[i] += __shfl_xor(ps[i], 32);
    }
    if (rquad == 0) {
#pragma unroll
        for (int i = 0; i < 8; i++) {
            redM[w * 128 + c0 + i] = pm[i];
            redS[w * 128 + c0 + i] = ps[i];
        }
    }
    __syncthreads();
    if (tid < 128) {
        float M = -BINF, S = 0.f;
#pragma unroll
        for (int w2 = 0; w2 < 4; w2++) {
            M = fmaxf(M, redM[w2 * 128 + tid]);
            S += redS[w2 * 128 + tid];
        }
        partM1[(size_t)bx * 128 + tid] = M;
        partS1[(size_t)bx * 128 + tid] = S;
    }

    // ---- dual GEMM over 96 rows: A2 = x1@W1'+b, B2 = x1@W2'
    f32x4 acc[2][2][6];
#pragma unroll
    for (int o = 0; o < 2; o++)
#pragma unroll
        for (int j = 0; j < 2; j++)
#pragma unroll
            for (int mf = 0; mf < 6; mf++) acc[o][j][mf] = (f32x4){0.f, 0.f, 0.f, 0.f};
    int row16 = lane & 15, kslot = lane >> 4;
    int swz = (row16 & 7) << 3;
#pragma unroll 1
    for (int kt = 0; kt < 4; kt++) {
        f16x8 wf0[2], wf1[2], xa[6];
#pragma unroll
        for (int j = 0; j < 2; j++) {
            wf0[j] = wfrag[((0 * 4 + kt) * 8 + (w * 2 + j)) * 64 + lane];
            wf1[j] = wfrag[((1 * 4 + kt) * 8 + (w * 2 + j)) * 64 + lane];
        }
#pragma unroll
        for (int mf = 0; mf < 6; mf++)
            xa[mf] = *(const f16x8*)&x1t[((mf * 16 + row16) * 128 + kt * 32 + kslot * 8) ^ swz];
#pragma unroll
        for (int mf = 0; mf < 6; mf++)
#pragma unroll
            for (int j = 0; j < 2; j++) {
                acc[0][j][mf] = __builtin_amdgcn_mfma_f32_16x16x32_f16(xa[mf], wf0[j], acc[0][j][mf], 0, 0, 0);
                acc[1][j][mf] = __builtin_amdgcn_mfma_f32_16x16x32_f16(xa[mf], wf1[j], acc[1][j][mf], 0, 0, 0);
            }
    }
    // epilogue -> LDS (B2 all 96 rows; A2 interior 64 rows)
#pragma unroll
    for (int j = 0; j < 2; j++) {
        int col = w * 32 + j * 16 + (lane & 15);
        float bias = cb[col];
#pragma unroll
        for (int mf = 0; mf < 6; mf++) {
            int rloc = mf * 16 + ((lane >> 4) << 2);
#pragma unroll
            for (int q = 0; q < 4; q++) {
                int hrow = rloc + q;           // [0,96)
                *(f16*)(b2 + hrow * BWS + col * 2) = (f16)acc[1][j][mf][q];
                if (hrow >= 16 && hrow < 80)
                    *(f16*)(a2 + (hrow - 16) * BWS + col * 2) = (f16)(acc[0][j][mf][q] + bias);
            }
        }
    }
    __syncthreads();

    // ---- gather2 + pool (interior 64 rows), all from LDS
#pragma unroll
    for (int i = 0; i < 8; i++) { pm[i] = -BINF; ps[i] = 0.f; }
#pragma unroll 1
    for (int rr = 0; rr < 4; rr++) {
        int rl = w * 16 + rr * 4 + rquad;      // [0,64)
        int grow = r0 + rl;
        int4 ov = *(const int4*)(nbroff + (size_t)grow * 16);
        const int* ow = (const int*)&ov;
        f16x8 m;
#pragma unroll
        for (int i = 0; i < 8; i++) m[i] = (f16)(-INFINITY);
#pragma unroll
        for (int q = 0; q < 16; q++) {
            int off = (int)(signed char)((ow[q >> 2] >> ((q & 3) * 8)) & 0xff);
            int hn = rl + 16 + off;            // [0,96)
            f16x8 bv = *(const f16x8*)(b2 + hn * BWS + c0 * 2);
            m = __builtin_elementwise_max(m, bv);
        }
        f16x8 av = *(const f16x8*)(a2 + rl * BWS + c0 * 2);
#pragma unroll
        for (int i = 0; i < 8; i++) {
            float v = fmaxf((float)av[i] + (float)m[i], 0.0f);
            pm[i] = fmaxf(pm[i], v);
            ps[i] += v;
        }
    }
#pragma unroll
    for (int i = 0; i < 8; i++) {
        pm[i] = fmaxf(pm[i], __shfl_xor(pm[i], 16));
        pm[i] = fmaxf(pm[i], __shfl_xor(pm[i], 32));
        ps[i] += __shfl_xor(ps[i], 16);
        ps[i] += __shfl_xor(ps[i], 32);
    }
    __syncthreads();                           // red arrays were read above; safe to overwrite
    if (rquad == 0) {
#pragma unroll
        for (int i = 0; i < 8; i++) {
            redM[w * 128 + c0 + i] = pm[i];
            redS[w * 128 + c0 + i] = ps[i];
        }
    }
    __syncthreads();
    if (tid < 128) {
        float M = -BINF, S = 0.f;
#pragma unroll
        for (int w2 = 0; w2 < 4; w2++) {
            M = fmaxf(M, redM[w2 * 128 + tid]);
            S += redS[w2 * 128 + tid];
        }
        partM2[(size_t)bx * 128 + tid] = M;
        partS2[(size_t)bx * 128 + tid] = S;
    }
}

// ---------------------------------------------------------------- final head
__global__ __launch_bounds__(256) void k_final(const float* __restrict__ partM1,
                                               const float* __restrict__ partS1,
                                               const float* __restrict__ partM2,
                                               const float* __restrict__ partS2,
                                               const float* __restrict__ fg_lw,
                                               const float* __restrict__ fg_lb,
                                               const float* __restrict__ fg_gw,
                                               const float* __restrict__ fg_gb,
                                               const float* __restrict__ out_w,
                                               const float* __restrict__ out_b,
                                               float* __restrict__ out) {
    __shared__ float pooled[512];
    __shared__ float linv[128], gatev[128];
    __shared__ float gluv[128];
    __shared__ float lg[2];
    int g = blockIdx.x, tid = threadIdx.x;

    const float* pM = (tid < 128) ? partM1 : partM2;
    const float* pS = (tid < 128) ? partS1 : partS2;
    int cc = tid & 127;
    float mx = -BINF, sm = 0.0f;
    for (int ch = 0; ch < 16; ch++) {
        mx = fmaxf(mx, pM[(size_t)(g * 16 + ch) * 128 + cc]);
        sm += pS[(size_t)(g * 16 + ch) * 128 + cc];
    }
    pooled[tid] = mx;
    pooled[256 + tid] = sm * (1.0f / 1024.0f);
    __syncthreads();

    float acc = 0.0f;
    if (tid < 128) {
        for (int k = 0; k < 512; k++) acc = fmaf(pooled[k], fg_lw[k * 128 + tid], acc);
        linv[tid] = acc + fg_lb[tid];
    } else {
        int c = tid - 128;
        for (int k = 0; k < 512; k++) acc = fmaf(pooled[k], fg_gw[k * 128 + c], acc);
        gatev[c] = acc + fg_gb[c];
    }
    __syncthreads();
    if (tid < 128) gluv[tid] = linv[tid] / (1.0f + expf(-gatev[tid]));
    __syncthreads();
    if (tid < 2) {
        float s = out_b[tid];
        for (int c = 0; c < 128; c++) s = fmaf(gluv[c], out_w[c * 2 + tid], s);
        lg[tid] = s;
    }
    __syncthreads();
    if (tid < 2) {
        float m = fmaxf(lg[0], lg[1]);
        float lse = m + logf(expf(lg[0] - m) + expf(lg[1] - m));
        out[g * 2 + tid] = lg[tid] - lse;
    }
}

// ---------------------------------------------------------------- launch
extern "C" void kernel_launch(void* const* d_in, const int* in_sizes, int n_in,
                              void* d_out, int out_size, void* d_ws, size_t ws_size,
                              hipStream_t stream) {
    const float* x     = (const float*)d_in[0];
    const float* te_w  = (const float*)d_in[1];
    const float* te_b  = (const float*)d_in[2];
    const float* ig_lw = (const float*)d_in[3];
    const float* ig_lb = (const float*)d_in[4];
    const float* ig_gw = (const float*)d_in[5];
    const float* ig_gb = (const float*)d_in[6];
    const float* c1_w  = (const float*)d_in[7];
    const float* c1_b  = (const float*)d_in[8];
    const float* c2_w  = (const float*)d_in[9];
    const float* c2_b  = (const float*)d_in[10];
    const float* fg_lw = (const float*)d_in[11];
    const float* fg_lb = (const float*)d_in[12];
    const float* fg_gw = (const float*)d_in[13];
    const float* fg_gb = (const float*)d_in[14];
    const float* out_w = (const float*)d_in[15];
    const float* out_b = (const float*)d_in[16];
    float* out = (float*)d_out;

    // workspace layout (~37 MB)
    char* p = (char*)d_ws;
    const size_t T16 = (size_t)NN * HID * sizeof(f16);   // 16 MB
    f16* A1 = (f16*)p; p += T16;
    f16* B1 = (f16*)p; p += T16;
    int* sidxg = (int*)p;            p += (size_t)NN * 4;
    signed char* nbroff = (signed char*)p; p += (size_t)NN * KNN;
    float* partM1 = (float*)p;       p += (size_t)1024 * 128 * 4;
    float* partS1 = (float*)p;       p += (size_t)1024 * 128 * 4;
    float* partM2 = (float*)p;       p += (size_t)1024 * 128 * 4;
    float* partS2 = (float*)p;       p += (size_t)1024 * 128 * 4;
    f16* gfrag = (f16*)p;            p += 16384 * 2;
    f16* f1 = (f16*)p;               p += 32768 * 2;
    f16* f2 = (f16*)p;               p += 32768 * 2;

    k_topk<<<NG + 80, 1024, 0, stream>>>(x, sidxg, nbroff, ig_lw, ig_gw,
                                         c1_w, c2_w, gfrag, f1, f2);
    k_fuse1<<<NN / 64, 256, 0, stream>>>(x, te_w, te_b, (const f16x8*)gfrag,
                                         ig_lb, ig_gb, sidxg, (const f16x8*)f1,
                                         c1_b, A1, B1);
    k_megac2<<<NN / 64, 256, 0, stream>>>(A1, B1, nbroff, (const f16x8*)f2,
                                          c2_b, partM1, partS1, partM2, partS2);
    k_final<<<NG, 256, 0, stream>>>(partM1, partS1, partM2, partS2,
                                    fg_lw, fg_lb, fg_gw, fg_gb, out_w, out_b, out);
}